// Round 2
// baseline (220.232 us; speedup 1.0000x reference)
//
#include <hip/hip_runtime.h>
#include <hip/hip_bf16.h>

// Problem dims (fixed)
#define BB   8
#define LL   32
#define NINV 64
#define NOUTV 16
#define DINV 128
#define EE   64
#define DCV  512

#define EPSF 1e-8f
#define LBDF 1e-3f
// 32 * ln(2*pi)
#define SUM_LN2PI 58.8120661250990508f

// ---------------------------------------------------------------------------
// Kernel 1: c[b,l,e] = ctx[b,l,:]@Wc + bc   (blocks 0..255)
//           actn[b,n] = sigmoid(inu[b,n,:]@Wa + ba)  (blocks 256..263)
// ---------------------------------------------------------------------------
__global__ __launch_bounds__(64) void prep_kernel(
    const float* __restrict__ ctx, const float* __restrict__ Wc, const float* __restrict__ bc,
    const float* __restrict__ inu, const float* __restrict__ Wa, const float* __restrict__ ba,
    float* __restrict__ c_out, float* __restrict__ actn_out)
{
    const int blk = blockIdx.x;
    const int t = threadIdx.x;
    __shared__ float row[DCV];
    if (blk < BB * LL) {
        const float* cr = ctx + (size_t)blk * DCV;
        #pragma unroll
        for (int i = 0; i < DCV / 64; ++i) row[t + 64 * i] = cr[t + 64 * i];
        __syncthreads();
        float acc = bc[t];
        for (int d = 0; d < DCV; ++d) acc = fmaf(row[d], Wc[d * EE + t], acc);
        c_out[blk * EE + t] = acc;
    } else {
        const int b = blk - BB * LL;
        const float* ir = inu + ((size_t)b * NINV + t) * DINV;
        float acc = ba[0];
        for (int d = 0; d < DINV; ++d) acc = fmaf(ir[d], Wa[d], acc);
        actn_out[b * NINV + t] = 1.0f / (1.0f + expf(-acc));
    }
}

// ---------------------------------------------------------------------------
// Kernel 2: block (n,o):
//   priors[b,e] = sum_d inu[b,n,d] * rw[n,o,d,e]   (8x128 @ 128x64)
//   u[b,n,o,e]  = priors[b,:] @ Wu + bu
// ---------------------------------------------------------------------------
__global__ __launch_bounds__(256) void priors_u_kernel(
    const float* __restrict__ inu, const float* __restrict__ rw,
    const float* __restrict__ Wu, const float* __restrict__ bu,
    float* __restrict__ u_out)
{
    const int no = blockIdx.x;      // n*16+o
    const int n  = no >> 4;
    const int oo = no & 15;
    const int tid = threadIdx.x;

    __shared__ float inu_sh[BB * DINV];   // 4 KB
    __shared__ float pri_sh[BB * EE];     // 2 KB

    {   // stage inu[:, n, :]
        const int b = tid >> 5;
        const int i = (tid & 31) * 4;
        const float4 s = *(const float4*)(inu + ((size_t)b * NINV + n) * DINV + i);
        *(float4*)(inu_sh + b * DINV + i) = s;
    }
    __syncthreads();

    const int bg = tid >> 6;   // 0..3 -> handles b = 2bg, 2bg+1
    const int e  = tid & 63;
    const float* rwp = rw + (size_t)no * DINV * EE + e;
    const float* r0 = inu_sh + (bg * 2) * DINV;
    const float* r1 = inu_sh + (bg * 2 + 1) * DINV;
    float a0 = 0.0f, a1 = 0.0f;
    for (int d = 0; d < DINV; ++d) {
        const float w = rwp[d * EE];
        a0 = fmaf(r0[d], w, a0);
        a1 = fmaf(r1[d], w, a1);
    }
    pri_sh[(bg * 2) * EE + e] = a0;
    pri_sh[(bg * 2 + 1) * EE + e] = a1;
    __syncthreads();

    float b0 = bu[e], b1 = b0;
    const float* p0 = pri_sh + (bg * 2) * EE;
    const float* p1 = pri_sh + (bg * 2 + 1) * EE;
    for (int e1 = 0; e1 < EE; ++e1) {
        const float w = Wu[e1 * EE + e];
        b0 = fmaf(p0[e1], w, b0);
        b1 = fmaf(p1[e1], w, b1);
    }
    u_out[(((size_t)(bg * 2) * NINV + n) * NOUTV + oo) * EE + e] = b0;
    u_out[(((size_t)(bg * 2 + 1) * NINV + n) * NOUTV + oo) * EE + e] = b1;
}

// ---------------------------------------------------------------------------
// Kernel 3: one 1024-thread workgroup per (b,l).
// Thread (n,o) holds votes[n,o,0:64] in registers.
// ---------------------------------------------------------------------------
__global__ __launch_bounds__(1024) void votes_em_kernel(
    const float* __restrict__ u_all, const float* __restrict__ c_all,
    const float* __restrict__ actn_all, const unsigned char* __restrict__ mask_all,
    const float* __restrict__ Wv, const float* __restrict__ bv,
    const float* __restrict__ beta_u, const float* __restrict__ beta_a,
    float* __restrict__ out_mu, float* __restrict__ out_r)
{
    const int bl = blockIdx.x;           // 0..255
    const int b = bl >> 5;
    const int tid = threadIdx.x;
    const int n = tid >> 4;
    const int o = tid & 15;
    const int lane = tid & 63;
    const int wid = tid >> 6;            // wave id 0..15
    const int o_f = wid;                 // final-reduce mapping
    const int e_f = lane;

    __shared__ float c_sh[EE];
    __shared__ float actn_sh[NINV];
    __shared__ float red[16][NOUTV][EE + 4];     // 69.6 KB, padded rows (bank-safe)
    __shared__ float red_s[16][NOUTV];
    __shared__ float mu_sh[NOUTV][EE + 4];
    __shared__ float inv2s_sh[NOUTV][EE + 4];
    __shared__ float sumhl_sh[NOUTV];
    __shared__ float logact_sh[NOUTV];

    if (tid < EE) c_sh[tid] = c_all[bl * EE + tid];
    else if (tid >= 64 && tid < 128) actn_sh[tid - 64] = actn_all[b * NINV + (tid - 64)];
    __syncthreads();

    // ---- votes[n,o,e] = sum_e1 tanh(u[e1]+c[e1]) * Wv[e1][e] + bv[e] ----
    float v[EE];
    #pragma unroll
    for (int e = 0; e < EE; ++e) v[e] = bv[e];          // wave-uniform -> s_load
    const float4* u4 = (const float4*)(u_all + (((size_t)b * NINV + n) * NOUTV + o) * EE);
    for (int cc = 0; cc < 16; ++cc) {
        const float4 uu = u4[cc];
        #pragma unroll
        for (int j = 0; j < 4; ++j) {
            const int e1 = cc * 4 + j;
            const float x = ((const float*)&uu)[j] + c_sh[e1];
            const float tt = tanhf(x);
            const float* wrow = Wv + e1 * EE;           // wave-uniform address
            #pragma unroll
            for (int e = 0; e < EE; ++e) v[e] = fmaf(tt, wrow[e], v[e]);
        }
    }

    const unsigned char msk = mask_all[b * NINV + n];
    float r_local = 1.0f / 16.0f;

    for (int it = 0; it < 3; ++it) {
        // ---- ar / r1 ----
        const float a_n = actn_sh[n];
        float ar = a_n * r_local;
        float s16 = ar;
        s16 += __shfl_xor(s16, 1, 64);
        s16 += __shfl_xor(s16, 2, 64);
        s16 += __shfl_xor(s16, 4, 64);
        s16 += __shfl_xor(s16, 8, 64);
        ar = ar / (s16 + EPSF);
        float p = ar;
        p += __shfl_xor(p, 16, 64);
        p += __shfl_xor(p, 32, 64);
        if (lane < NOUTV) red_s[wid][lane] = p;
        __syncthreads();                                  // (1)
        float arsum = 0.0f;
        #pragma unroll
        for (int w2 = 0; w2 < 16; ++w2) arsum += red_s[w2][o];
        const float r1 = ar / (arsum + EPSF);

        // ---- mu: sum_n r1*v ----
        float wacc[EE];
        #pragma unroll
        for (int e = 0; e < EE; ++e) {
            float t2 = r1 * v[e];
            t2 += __shfl_xor(t2, 16, 64);
            t2 += __shfl_xor(t2, 32, 64);
            wacc[e] = t2;
        }
        if (lane < NOUTV) {
            #pragma unroll
            for (int e4 = 0; e4 < EE / 4; ++e4)
                *(float4*)&red[wid][lane][e4 * 4] =
                    make_float4(wacc[e4*4+0], wacc[e4*4+1], wacc[e4*4+2], wacc[e4*4+3]);
        }
        __syncthreads();                                  // (2)
        float mu_f = 0.0f;
        #pragma unroll
        for (int w2 = 0; w2 < 16; ++w2) mu_f += red[w2][o_f][e_f];

        if (it == 2) {
            out_mu[bl * 1024 + tid] = mu_f;
            break;
        }
        mu_sh[o_f][e_f] = mu_f;
        __syncthreads();                                  // (3)

        // ---- sigma: sum_n r1*(v-mu)^2 ----
        #pragma unroll
        for (int e4 = 0; e4 < EE / 4; ++e4) {
            const float4 m4 = *(const float4*)&mu_sh[o][e4 * 4];
            #pragma unroll
            for (int k = 0; k < 4; ++k) {
                const float d = v[e4 * 4 + k] - ((const float*)&m4)[k];
                float t2 = r1 * d * d;
                t2 += __shfl_xor(t2, 16, 64);
                t2 += __shfl_xor(t2, 32, 64);
                wacc[e4 * 4 + k] = t2;
            }
        }
        if (lane < NOUTV) {
            #pragma unroll
            for (int e4 = 0; e4 < EE / 4; ++e4)
                *(float4*)&red[wid][lane][e4 * 4] =
                    make_float4(wacc[e4*4+0], wacc[e4*4+1], wacc[e4*4+2], wacc[e4*4+3]);
        }
        __syncthreads();                                  // (4)
        float sig = 0.0f;
        #pragma unroll
        for (int w2 = 0; w2 < 16; ++w2) sig += red[w2][o_f][e_f];
        const float s = sig + EPSF;
        const float hl = 0.5f * logf(s);
        inv2s_sh[o_f][e_f] = 0.5f / s;
        float arsum_f = 0.0f;
        #pragma unroll
        for (int w2 = 0; w2 < 16; ++w2) arsum_f += red_s[w2][o_f];
        float sh = hl;
        sh += __shfl_xor(sh, 1, 64);
        sh += __shfl_xor(sh, 2, 64);
        sh += __shfl_xor(sh, 4, 64);
        sh += __shfl_xor(sh, 8, 64);
        sh += __shfl_xor(sh, 16, 64);
        sh += __shfl_xor(sh, 32, 64);
        if (lane == 0) {
            sumhl_sh[o_f] = sh;
            const float costsum = 64.0f * beta_u[o_f] + arsum_f * sh;
            const float xact = LBDF * (beta_a[o_f] - costsum);
            const float actn = 1.0f / (1.0f + expf(-xact));
            logact_sh[o_f] = logf(actn);
        }
        __syncthreads();                                  // (5)

        // ---- e_step ----
        float acc2 = 0.0f;
        #pragma unroll
        for (int e4 = 0; e4 < EE / 4; ++e4) {
            const float4 m4 = *(const float4*)&mu_sh[o][e4 * 4];
            const float4 i4 = *(const float4*)&inv2s_sh[o][e4 * 4];
            #pragma unroll
            for (int k = 0; k < 4; ++k) {
                const float d = v[e4 * 4 + k] - ((const float*)&m4)[k];
                acc2 = fmaf(d * d, ((const float*)&i4)[k], acc2);
            }
        }
        float logap = -acc2 - sumhl_sh[o] - SUM_LN2PI + logact_sh[o];
        if (msk) logap = -10000.0f;
        float mx = logap;
        mx = fmaxf(mx, __shfl_xor(mx, 1, 64));
        mx = fmaxf(mx, __shfl_xor(mx, 2, 64));
        mx = fmaxf(mx, __shfl_xor(mx, 4, 64));
        mx = fmaxf(mx, __shfl_xor(mx, 8, 64));
        const float ex = expf(logap - mx);
        float se = ex;
        se += __shfl_xor(se, 1, 64);
        se += __shfl_xor(se, 2, 64);
        se += __shfl_xor(se, 4, 64);
        se += __shfl_xor(se, 8, 64);
        r_local = ex / se;
    }

    out_r[bl * 1024 + tid] = r_local;
}

// ---------------------------------------------------------------------------
extern "C" void kernel_launch(void* const* d_in, const int* in_sizes, int n_in,
                              void* d_out, int out_size, void* d_ws, size_t ws_size,
                              hipStream_t stream) {
    const float* inu            = (const float*)d_in[0];
    const unsigned char* mask   = (const unsigned char*)d_in[1];
    const float* ctx            = (const float*)d_in[2];
    const float* rw             = (const float*)d_in[3];
    const float* Wu             = (const float*)d_in[4];
    const float* bu             = (const float*)d_in[5];
    const float* Wc             = (const float*)d_in[6];
    const float* bc             = (const float*)d_in[7];
    const float* Wv             = (const float*)d_in[8];
    const float* bv             = (const float*)d_in[9];
    const float* Wa             = (const float*)d_in[10];
    const float* ba             = (const float*)d_in[11];
    const float* beta_u         = (const float*)d_in[12];
    const float* beta_a         = (const float*)d_in[13];

    float* u_ws = (float*)d_ws;                       // B*NIN*NOUT*E = 524288 f32
    float* c_ws = u_ws + (size_t)BB * NINV * NOUTV * EE;
    float* a_ws = c_ws + (size_t)BB * LL * EE;        // B*NIN = 512 f32

    float* out_mu = (float*)d_out;
    float* out_r  = out_mu + (size_t)BB * LL * NOUTV * EE;

    prep_kernel<<<BB * LL + BB, 64, 0, stream>>>(ctx, Wc, bc, inu, Wa, ba, c_ws, a_ws);
    priors_u_kernel<<<NINV * NOUTV, 256, 0, stream>>>(inu, rw, Wu, bu, u_ws);
    votes_em_kernel<<<BB * LL, 1024, 0, stream>>>(u_ws, c_ws, a_ws, mask, Wv, bv,
                                                  beta_u, beta_a, out_mu, out_r);
}

// Round 3
// 101.874 us; speedup vs baseline: 2.1618x; 2.1618x over previous
//
#include <hip/hip_runtime.h>
#include <hip/hip_bf16.h>

// Problem dims (fixed)
#define BB   8
#define LL   32
#define NINV 64
#define NOUTV 16
#define DINV 128
#define EE   64
#define DCV  512

#define EPSF 1e-8f
#define LBDF 1e-3f
// 32 * ln(2*pi)
#define SUM_LN2PI 58.8120661250990508f

// ---------------------------------------------------------------------------
// Kernel 1: c[b,l,e] = ctx[b,l,:]@Wc + bc   (blocks 0..255)
//           actn[b,n] = sigmoid(inu[b,n,:]@Wa + ba)  (blocks 256..263)
// ---------------------------------------------------------------------------
__global__ __launch_bounds__(64) void prep_kernel(
    const float* __restrict__ ctx, const float* __restrict__ Wc, const float* __restrict__ bc,
    const float* __restrict__ inu, const float* __restrict__ Wa, const float* __restrict__ ba,
    float* __restrict__ c_out, float* __restrict__ actn_out)
{
    const int blk = blockIdx.x;
    const int t = threadIdx.x;
    __shared__ float row[DCV];
    if (blk < BB * LL) {
        const float* cr = ctx + (size_t)blk * DCV;
        #pragma unroll
        for (int i = 0; i < DCV / 64; ++i) row[t + 64 * i] = cr[t + 64 * i];
        __syncthreads();
        float acc = bc[t];
        for (int d = 0; d < DCV; ++d) acc = fmaf(row[d], Wc[d * EE + t], acc);
        c_out[blk * EE + t] = acc;
    } else {
        const int b = blk - BB * LL;
        const float* ir = inu + ((size_t)b * NINV + t) * DINV;
        float acc = ba[0];
        for (int d = 0; d < DINV; ++d) acc = fmaf(ir[d], Wa[d], acc);
        actn_out[b * NINV + t] = 1.0f / (1.0f + expf(-acc));
    }
}

// ---------------------------------------------------------------------------
// Kernel 2: block (n,o):
//   priors[b,e] = sum_d inu[b,n,d] * rw[n,o,d,e]   (8x128 @ 128x64)
//   u[b,n,o,e]  = priors[b,:] @ Wu + bu
// ---------------------------------------------------------------------------
__global__ __launch_bounds__(256) void priors_u_kernel(
    const float* __restrict__ inu, const float* __restrict__ rw,
    const float* __restrict__ Wu, const float* __restrict__ bu,
    float* __restrict__ u_out)
{
    const int no = blockIdx.x;      // n*16+o
    const int n  = no >> 4;
    const int oo = no & 15;
    const int tid = threadIdx.x;

    __shared__ float inu_sh[BB * DINV];   // 4 KB
    __shared__ float pri_sh[BB * EE];     // 2 KB

    {   // stage inu[:, n, :]
        const int b = tid >> 5;
        const int i = (tid & 31) * 4;
        const float4 s = *(const float4*)(inu + ((size_t)b * NINV + n) * DINV + i);
        *(float4*)(inu_sh + b * DINV + i) = s;
    }
    __syncthreads();

    const int bg = tid >> 6;   // 0..3 -> handles b = 2bg, 2bg+1
    const int e  = tid & 63;
    const float* rwp = rw + (size_t)no * DINV * EE + e;
    const float* r0 = inu_sh + (bg * 2) * DINV;
    const float* r1 = inu_sh + (bg * 2 + 1) * DINV;
    float a0 = 0.0f, a1 = 0.0f;
    for (int d = 0; d < DINV; ++d) {
        const float w = rwp[d * EE];
        a0 = fmaf(r0[d], w, a0);
        a1 = fmaf(r1[d], w, a1);
    }
    pri_sh[(bg * 2) * EE + e] = a0;
    pri_sh[(bg * 2 + 1) * EE + e] = a1;
    __syncthreads();

    float b0 = bu[e], b1 = b0;
    const float* p0 = pri_sh + (bg * 2) * EE;
    const float* p1 = pri_sh + (bg * 2 + 1) * EE;
    for (int e1 = 0; e1 < EE; ++e1) {
        const float w = Wu[e1 * EE + e];
        b0 = fmaf(p0[e1], w, b0);
        b1 = fmaf(p1[e1], w, b1);
    }
    u_out[(((size_t)(bg * 2) * NINV + n) * NOUTV + oo) * EE + e] = b0;
    u_out[(((size_t)(bg * 2 + 1) * NINV + n) * NOUTV + oo) * EE + e] = b1;
}

// ---------------------------------------------------------------------------
// Kernel 3: one 1024-thread workgroup per (b,l).
// Thread (n,o) holds votes[n,o,0:64] in registers.
// __launch_bounds__(1024, 4): 16 waves/block = 4 waves/SIMD -> 128 VGPR cap,
// enough for v[64] + overhead without spilling (round-2 profile showed the
// compiler capping at 64 VGPR and spilling ~600 MB to scratch).
// ---------------------------------------------------------------------------
__global__ __launch_bounds__(1024, 4) void votes_em_kernel(
    const float* __restrict__ u_all, const float* __restrict__ c_all,
    const float* __restrict__ actn_all, const unsigned char* __restrict__ mask_all,
    const float* __restrict__ Wv, const float* __restrict__ bv,
    const float* __restrict__ beta_u, const float* __restrict__ beta_a,
    float* __restrict__ out_mu, float* __restrict__ out_r)
{
    const int bl = blockIdx.x;           // 0..255
    const int b = bl >> 5;
    const int tid = threadIdx.x;
    const int n = tid >> 4;
    const int o = tid & 15;
    const int lane = tid & 63;
    const int wid = tid >> 6;            // wave id 0..15
    const int o_f = wid;                 // final-reduce mapping
    const int e_f = lane;

    __shared__ float c_sh[EE];
    __shared__ float actn_sh[NINV];
    __shared__ float red[16][NOUTV][EE + 4];     // 69.6 KB, padded rows (bank-safe)
    __shared__ float red_s[16][NOUTV];
    __shared__ float mu_sh[NOUTV][EE + 4];
    __shared__ float inv2s_sh[NOUTV][EE + 4];
    __shared__ float sumhl_sh[NOUTV];
    __shared__ float logact_sh[NOUTV];

    if (tid < EE) c_sh[tid] = c_all[bl * EE + tid];
    else if (tid >= 64 && tid < 128) actn_sh[tid - 64] = actn_all[b * NINV + (tid - 64)];
    __syncthreads();

    // ---- votes[n,o,e] = sum_e1 tanh(u[e1]+c[e1]) * Wv[e1][e] + bv[e] ----
    float v[EE];
    #pragma unroll
    for (int e = 0; e < EE; ++e) v[e] = bv[e];          // wave-uniform -> s_load
    const float4* u4 = (const float4*)(u_all + (((size_t)b * NINV + n) * NOUTV + o) * EE);
    float4 uu = u4[0];
    for (int cc = 0; cc < 16; ++cc) {
        const float4 nxt = (cc < 15) ? u4[cc + 1] : uu;   // prefetch
        #pragma unroll
        for (int j = 0; j < 4; ++j) {
            const int e1 = cc * 4 + j;
            const float x = ((const float*)&uu)[j] + c_sh[e1];
            // tanh(x) = 1 - 2/(e^{2x}+1); |x| < ~0.7 here, error ~1e-7
            const float tt = 1.0f - 2.0f / (__expf(2.0f * x) + 1.0f);
            const float* wrow = Wv + e1 * EE;           // wave-uniform address
            #pragma unroll
            for (int e = 0; e < EE; ++e) v[e] = fmaf(tt, wrow[e], v[e]);
        }
        uu = nxt;
    }

    const unsigned char msk = mask_all[b * NINV + n];
    float r_local = 1.0f / 16.0f;

    for (int it = 0; it < 3; ++it) {
        // ---- ar / r1 ----
        const float a_n = actn_sh[n];
        float ar = a_n * r_local;
        float s16 = ar;
        s16 += __shfl_xor(s16, 1, 64);
        s16 += __shfl_xor(s16, 2, 64);
        s16 += __shfl_xor(s16, 4, 64);
        s16 += __shfl_xor(s16, 8, 64);
        ar = ar / (s16 + EPSF);
        float p = ar;
        p += __shfl_xor(p, 16, 64);
        p += __shfl_xor(p, 32, 64);
        if (lane < NOUTV) red_s[wid][lane] = p;
        __syncthreads();                                  // (1)
        float arsum = 0.0f;
        #pragma unroll
        for (int w2 = 0; w2 < 16; ++w2) arsum += red_s[w2][o];
        const float r1 = ar / (arsum + EPSF);

        // ---- mu: sum_n r1*v  (reduce per 4-chunk, no wacc array) ----
        #pragma unroll
        for (int e4 = 0; e4 < EE / 4; ++e4) {
            float t0 = r1 * v[e4 * 4 + 0];
            float t1 = r1 * v[e4 * 4 + 1];
            float t2 = r1 * v[e4 * 4 + 2];
            float t3 = r1 * v[e4 * 4 + 3];
            t0 += __shfl_xor(t0, 16, 64); t0 += __shfl_xor(t0, 32, 64);
            t1 += __shfl_xor(t1, 16, 64); t1 += __shfl_xor(t1, 32, 64);
            t2 += __shfl_xor(t2, 16, 64); t2 += __shfl_xor(t2, 32, 64);
            t3 += __shfl_xor(t3, 16, 64); t3 += __shfl_xor(t3, 32, 64);
            if (lane < NOUTV)
                *(float4*)&red[wid][lane][e4 * 4] = make_float4(t0, t1, t2, t3);
        }
        __syncthreads();                                  // (2)
        float mu_f = 0.0f;
        #pragma unroll
        for (int w2 = 0; w2 < 16; ++w2) mu_f += red[w2][o_f][e_f];

        if (it == 2) {
            out_mu[bl * 1024 + tid] = mu_f;
            break;
        }
        mu_sh[o_f][e_f] = mu_f;
        __syncthreads();                                  // (3)

        // ---- sigma: sum_n r1*(v-mu)^2 ----
        #pragma unroll
        for (int e4 = 0; e4 < EE / 4; ++e4) {
            const float4 m4 = *(const float4*)&mu_sh[o][e4 * 4];
            float d0 = v[e4 * 4 + 0] - m4.x;
            float d1 = v[e4 * 4 + 1] - m4.y;
            float d2 = v[e4 * 4 + 2] - m4.z;
            float d3 = v[e4 * 4 + 3] - m4.w;
            float t0 = r1 * d0 * d0;
            float t1 = r1 * d1 * d1;
            float t2 = r1 * d2 * d2;
            float t3 = r1 * d3 * d3;
            t0 += __shfl_xor(t0, 16, 64); t0 += __shfl_xor(t0, 32, 64);
            t1 += __shfl_xor(t1, 16, 64); t1 += __shfl_xor(t1, 32, 64);
            t2 += __shfl_xor(t2, 16, 64); t2 += __shfl_xor(t2, 32, 64);
            t3 += __shfl_xor(t3, 16, 64); t3 += __shfl_xor(t3, 32, 64);
            if (lane < NOUTV)
                *(float4*)&red[wid][lane][e4 * 4] = make_float4(t0, t1, t2, t3);
        }
        __syncthreads();                                  // (4)
        float sig = 0.0f;
        #pragma unroll
        for (int w2 = 0; w2 < 16; ++w2) sig += red[w2][o_f][e_f];
        const float s = sig + EPSF;
        const float hl = 0.5f * logf(s);
        inv2s_sh[o_f][e_f] = 0.5f / s;
        float arsum_f = 0.0f;
        #pragma unroll
        for (int w2 = 0; w2 < 16; ++w2) arsum_f += red_s[w2][o_f];
        float sh = hl;
        sh += __shfl_xor(sh, 1, 64);
        sh += __shfl_xor(sh, 2, 64);
        sh += __shfl_xor(sh, 4, 64);
        sh += __shfl_xor(sh, 8, 64);
        sh += __shfl_xor(sh, 16, 64);
        sh += __shfl_xor(sh, 32, 64);
        if (lane == 0) {
            sumhl_sh[o_f] = sh;
            const float costsum = 64.0f * beta_u[o_f] + arsum_f * sh;
            const float xact = LBDF * (beta_a[o_f] - costsum);
            const float actn = 1.0f / (1.0f + expf(-xact));
            logact_sh[o_f] = logf(actn);
        }
        __syncthreads();                                  // (5)

        // ---- e_step ----
        float acc2 = 0.0f;
        #pragma unroll
        for (int e4 = 0; e4 < EE / 4; ++e4) {
            const float4 m4 = *(const float4*)&mu_sh[o][e4 * 4];
            const float4 i4 = *(const float4*)&inv2s_sh[o][e4 * 4];
            float d0 = v[e4 * 4 + 0] - m4.x;
            float d1 = v[e4 * 4 + 1] - m4.y;
            float d2 = v[e4 * 4 + 2] - m4.z;
            float d3 = v[e4 * 4 + 3] - m4.w;
            acc2 = fmaf(d0 * d0, i4.x, acc2);
            acc2 = fmaf(d1 * d1, i4.y, acc2);
            acc2 = fmaf(d2 * d2, i4.z, acc2);
            acc2 = fmaf(d3 * d3, i4.w, acc2);
        }
        float logap = -acc2 - sumhl_sh[o] - SUM_LN2PI + logact_sh[o];
        if (msk) logap = -10000.0f;
        float mx = logap;
        mx = fmaxf(mx, __shfl_xor(mx, 1, 64));
        mx = fmaxf(mx, __shfl_xor(mx, 2, 64));
        mx = fmaxf(mx, __shfl_xor(mx, 4, 64));
        mx = fmaxf(mx, __shfl_xor(mx, 8, 64));
        const float ex = expf(logap - mx);
        float se = ex;
        se += __shfl_xor(se, 1, 64);
        se += __shfl_xor(se, 2, 64);
        se += __shfl_xor(se, 4, 64);
        se += __shfl_xor(se, 8, 64);
        r_local = ex / se;
    }

    out_r[bl * 1024 + tid] = r_local;
}

// ---------------------------------------------------------------------------
extern "C" void kernel_launch(void* const* d_in, const int* in_sizes, int n_in,
                              void* d_out, int out_size, void* d_ws, size_t ws_size,
                              hipStream_t stream) {
    const float* inu            = (const float*)d_in[0];
    const unsigned char* mask   = (const unsigned char*)d_in[1];
    const float* ctx            = (const float*)d_in[2];
    const float* rw             = (const float*)d_in[3];
    const float* Wu             = (const float*)d_in[4];
    const float* bu             = (const float*)d_in[5];
    const float* Wc             = (const float*)d_in[6];
    const float* bc             = (const float*)d_in[7];
    const float* Wv             = (const float*)d_in[8];
    const float* bv             = (const float*)d_in[9];
    const float* Wa             = (const float*)d_in[10];
    const float* ba             = (const float*)d_in[11];
    const float* beta_u         = (const float*)d_in[12];
    const float* beta_a         = (const float*)d_in[13];

    float* u_ws = (float*)d_ws;                       // B*NIN*NOUT*E = 524288 f32
    float* c_ws = u_ws + (size_t)BB * NINV * NOUTV * EE;
    float* a_ws = c_ws + (size_t)BB * LL * EE;        // B*NIN = 512 f32

    float* out_mu = (float*)d_out;
    float* out_r  = out_mu + (size_t)BB * LL * NOUTV * EE;

    prep_kernel<<<BB * LL + BB, 64, 0, stream>>>(ctx, Wc, bc, inu, Wa, ba, c_ws, a_ws);
    priors_u_kernel<<<NINV * NOUTV, 256, 0, stream>>>(inu, rw, Wu, bu, u_ws);
    votes_em_kernel<<<BB * LL, 1024, 0, stream>>>(u_ws, c_ws, a_ws, mask, Wv, bv,
                                                  beta_u, beta_a, out_mu, out_r);
}

// Round 4
// 85.001 us; speedup vs baseline: 2.5909x; 1.1985x over previous
//
#include <hip/hip_runtime.h>
#include <hip/hip_bf16.h>

// Problem dims (fixed)
#define BB   8
#define LL   32
#define NINV 64
#define NOUTV 16
#define DINV 128
#define EE   64
#define DCV  512

#define EPSF 1e-8f
#define LBDF 1e-3f
// 32 * ln(2*pi)
#define SUM_LN2PI 58.8120661250990508f

// ---------------------------------------------------------------------------
// Kernel 1: c[b,l,e] = ctx[b,l,:]@Wc + bc   (blocks 0..255)
//           actn[b,n] = sigmoid(inu[b,n,:]@Wa + ba)  (blocks 256..263)
// ---------------------------------------------------------------------------
__global__ __launch_bounds__(64) void prep_kernel(
    const float* __restrict__ ctx, const float* __restrict__ Wc, const float* __restrict__ bc,
    const float* __restrict__ inu, const float* __restrict__ Wa, const float* __restrict__ ba,
    float* __restrict__ c_out, float* __restrict__ actn_out)
{
    const int blk = blockIdx.x;
    const int t = threadIdx.x;
    __shared__ float row[DCV];
    if (blk < BB * LL) {
        const float* cr = ctx + (size_t)blk * DCV;
        #pragma unroll
        for (int i = 0; i < DCV / 64; ++i) row[t + 64 * i] = cr[t + 64 * i];
        __syncthreads();
        float acc = bc[t];
        for (int d = 0; d < DCV; ++d) acc = fmaf(row[d], Wc[d * EE + t], acc);
        c_out[blk * EE + t] = acc;
    } else {
        const int b = blk - BB * LL;
        const float* ir = inu + ((size_t)b * NINV + t) * DINV;
        float acc = ba[0];
        for (int d = 0; d < DINV; ++d) acc = fmaf(ir[d], Wa[d], acc);
        actn_out[b * NINV + t] = 1.0f / (1.0f + expf(-acc));
    }
}

// ---------------------------------------------------------------------------
// Kernel 2: block (n,o):
//   priors[b,e] = sum_d inu[b,n,d] * rw[n,o,d,e]   (8x128 @ 128x64)
//   u[b,n,o,e]  = priors[b,:] @ Wu + bu
// ---------------------------------------------------------------------------
__global__ __launch_bounds__(256) void priors_u_kernel(
    const float* __restrict__ inu, const float* __restrict__ rw,
    const float* __restrict__ Wu, const float* __restrict__ bu,
    float* __restrict__ u_out)
{
    const int no = blockIdx.x;      // n*16+o
    const int n  = no >> 4;
    const int oo = no & 15;
    const int tid = threadIdx.x;

    __shared__ float inu_sh[BB * DINV];   // 4 KB
    __shared__ float pri_sh[BB * EE];     // 2 KB

    {   // stage inu[:, n, :]
        const int b = tid >> 5;
        const int i = (tid & 31) * 4;
        const float4 s = *(const float4*)(inu + ((size_t)b * NINV + n) * DINV + i);
        *(float4*)(inu_sh + b * DINV + i) = s;
    }
    __syncthreads();

    const int bg = tid >> 6;   // 0..3 -> handles b = 2bg, 2bg+1
    const int e  = tid & 63;
    const float* rwp = rw + (size_t)no * DINV * EE + e;
    const float* r0 = inu_sh + (bg * 2) * DINV;
    const float* r1 = inu_sh + (bg * 2 + 1) * DINV;
    float a0 = 0.0f, a1 = 0.0f;
    for (int d = 0; d < DINV; ++d) {
        const float w = rwp[d * EE];
        a0 = fmaf(r0[d], w, a0);
        a1 = fmaf(r1[d], w, a1);
    }
    pri_sh[(bg * 2) * EE + e] = a0;
    pri_sh[(bg * 2 + 1) * EE + e] = a1;
    __syncthreads();

    float b0 = bu[e], b1 = b0;
    const float* p0 = pri_sh + (bg * 2) * EE;
    const float* p1 = pri_sh + (bg * 2 + 1) * EE;
    for (int e1 = 0; e1 < EE; ++e1) {
        const float w = Wu[e1 * EE + e];
        b0 = fmaf(p0[e1], w, b0);
        b1 = fmaf(p1[e1], w, b1);
    }
    u_out[(((size_t)(bg * 2) * NINV + n) * NOUTV + oo) * EE + e] = b0;
    u_out[(((size_t)(bg * 2 + 1) * NINV + n) * NOUTV + oo) * EE + e] = b1;
}

// ---------------------------------------------------------------------------
// Kernel 3: one 512-thread workgroup per (b,l).
// 512 threads = 8 waves = 2 waves/SIMD at 1 block/CU -> 256-VGPR budget.
// Thread (w,l) owns TWO (n,o) pairs with the SAME o: n0=(w<<2)|(l>>4),
// n1=n0+32, o=l&15. v0[64]+v1[64] (~128 regs) now fit in ARCH VGPRs
// (round-3 profile: 1024-thread block capped at 64 arch VGPRs, v[] lived
// in AGPRs -> 3x instruction inflation on the 4096-FMA GEMM).
// ---------------------------------------------------------------------------
__global__ __launch_bounds__(512, 2) void votes_em_kernel(
    const float* __restrict__ u_all, const float* __restrict__ c_all,
    const float* __restrict__ actn_all, const unsigned char* __restrict__ mask_all,
    const float* __restrict__ Wv, const float* __restrict__ bv,
    const float* __restrict__ beta_u, const float* __restrict__ beta_a,
    float* __restrict__ out_mu, float* __restrict__ out_r)
{
    const int bl = blockIdx.x;           // 0..255
    const int b = bl >> 5;
    const int tid = threadIdx.x;
    const int lane = tid & 63;
    const int wid = tid >> 6;            // wave id 0..7
    const int o = lane & 15;
    const int n0 = (wid << 2) | (lane >> 4);   // 0..31
    const int n1 = n0 + 32;                    // 32..63
    const int e_f = lane;                      // finalize role: e = lane,
    const int o_f0 = wid;                      // o in {wid, wid+8}
    const int o_f1 = wid + 8;

    __shared__ float c_sh[EE];
    __shared__ float actn_sh[NINV];
    __shared__ float red[8][NOUTV][EE + 4];      // 34.8 KB
    __shared__ float red_s[8][NOUTV];
    __shared__ float mu_sh[NOUTV][EE + 4];
    __shared__ float inv2s_sh[NOUTV][EE + 4];
    __shared__ float sumhl_sh[NOUTV];
    __shared__ float logact_sh[NOUTV];

    if (tid < EE) c_sh[tid] = c_all[bl * EE + tid];
    else if (tid >= 64 && tid < 128) actn_sh[tid - 64] = actn_all[b * NINV + (tid - 64)];
    __syncthreads();

    // ---- votes[n,o,e] = sum_e1 tanh(u[e1]+c[e1]) * Wv[e1][e] + bv[e] ----
    float v0[EE], v1[EE];
    #pragma unroll
    for (int e = 0; e < EE; ++e) { v0[e] = bv[e]; v1[e] = v0[e]; }
    const float4* u4_0 = (const float4*)(u_all + (((size_t)b * NINV + n0) * NOUTV + o) * EE);
    const float4* u4_1 = (const float4*)(u_all + (((size_t)b * NINV + n1) * NOUTV + o) * EE);
    float4 uu0 = u4_0[0];
    float4 uu1 = u4_1[0];
    for (int cc = 0; cc < 16; ++cc) {
        const float4 nx0 = (cc < 15) ? u4_0[cc + 1] : uu0;
        const float4 nx1 = (cc < 15) ? u4_1[cc + 1] : uu1;
        #pragma unroll
        for (int j = 0; j < 4; ++j) {
            const int e1 = cc * 4 + j;
            const float ce = c_sh[e1];
            const float x0 = ((const float*)&uu0)[j] + ce;
            const float x1 = ((const float*)&uu1)[j] + ce;
            // tanh(x) = 1 - 2/(e^{2x}+1)
            const float t0 = 1.0f - 2.0f / (__expf(2.0f * x0) + 1.0f);
            const float t1 = 1.0f - 2.0f / (__expf(2.0f * x1) + 1.0f);
            const float* wrow = Wv + e1 * EE;           // wave-uniform -> s_load
            #pragma unroll
            for (int e = 0; e < EE; ++e) {
                const float w = wrow[e];
                v0[e] = fmaf(t0, w, v0[e]);
                v1[e] = fmaf(t1, w, v1[e]);
            }
        }
        uu0 = nx0;
        uu1 = nx1;
    }

    const unsigned char msk0 = mask_all[b * NINV + n0];
    const unsigned char msk1 = mask_all[b * NINV + n1];
    float r_loc0 = 1.0f / 16.0f;
    float r_loc1 = 1.0f / 16.0f;

    for (int it = 0; it < 3; ++it) {
        // ---- ar / r1 ----
        float ar0 = actn_sh[n0] * r_loc0;
        float ar1 = actn_sh[n1] * r_loc1;
        // normalize over o (lane&15 groups), per pair
        float s0 = ar0, s1 = ar1;
        s0 += __shfl_xor(s0, 1, 64);  s1 += __shfl_xor(s1, 1, 64);
        s0 += __shfl_xor(s0, 2, 64);  s1 += __shfl_xor(s1, 2, 64);
        s0 += __shfl_xor(s0, 4, 64);  s1 += __shfl_xor(s1, 4, 64);
        s0 += __shfl_xor(s0, 8, 64);  s1 += __shfl_xor(s1, 8, 64);
        ar0 = ar0 / (s0 + EPSF);
        ar1 = ar1 / (s1 + EPSF);
        // per-o partial sum over this wave's 8 n's (pairs share o)
        float p = ar0 + ar1;
        p += __shfl_xor(p, 16, 64);
        p += __shfl_xor(p, 32, 64);
        if (lane < NOUTV) red_s[wid][lane] = p;
        __syncthreads();                                  // (1)
        float arsum = 0.0f;
        #pragma unroll
        for (int w2 = 0; w2 < 8; ++w2) arsum += red_s[w2][o];
        const float inv_ars = 1.0f / (arsum + EPSF);
        const float r1_0 = ar0 * inv_ars;
        const float r1_1 = ar1 * inv_ars;

        // ---- mu: sum_n r1*v ----
        #pragma unroll
        for (int e4 = 0; e4 < EE / 4; ++e4) {
            float t0 = fmaf(r1_0, v0[e4 * 4 + 0], r1_1 * v1[e4 * 4 + 0]);
            float t1 = fmaf(r1_0, v0[e4 * 4 + 1], r1_1 * v1[e4 * 4 + 1]);
            float t2 = fmaf(r1_0, v0[e4 * 4 + 2], r1_1 * v1[e4 * 4 + 2]);
            float t3 = fmaf(r1_0, v0[e4 * 4 + 3], r1_1 * v1[e4 * 4 + 3]);
            t0 += __shfl_xor(t0, 16, 64); t0 += __shfl_xor(t0, 32, 64);
            t1 += __shfl_xor(t1, 16, 64); t1 += __shfl_xor(t1, 32, 64);
            t2 += __shfl_xor(t2, 16, 64); t2 += __shfl_xor(t2, 32, 64);
            t3 += __shfl_xor(t3, 16, 64); t3 += __shfl_xor(t3, 32, 64);
            if (lane < NOUTV)
                *(float4*)&red[wid][lane][e4 * 4] = make_float4(t0, t1, t2, t3);
        }
        __syncthreads();                                  // (2)
        float mu_f0 = 0.0f, mu_f1 = 0.0f;
        #pragma unroll
        for (int w2 = 0; w2 < 8; ++w2) {
            mu_f0 += red[w2][o_f0][e_f];
            mu_f1 += red[w2][o_f1][e_f];
        }

        if (it == 2) {
            out_mu[bl * 1024 + o_f0 * EE + e_f] = mu_f0;
            out_mu[bl * 1024 + o_f1 * EE + e_f] = mu_f1;
            break;
        }
        mu_sh[o_f0][e_f] = mu_f0;
        mu_sh[o_f1][e_f] = mu_f1;
        __syncthreads();                                  // (3)

        // ---- sigma: sum_n r1*(v-mu)^2 ----
        #pragma unroll
        for (int e4 = 0; e4 < EE / 4; ++e4) {
            const float4 m4 = *(const float4*)&mu_sh[o][e4 * 4];
            float d00 = v0[e4 * 4 + 0] - m4.x, d10 = v1[e4 * 4 + 0] - m4.x;
            float d01 = v0[e4 * 4 + 1] - m4.y, d11 = v1[e4 * 4 + 1] - m4.y;
            float d02 = v0[e4 * 4 + 2] - m4.z, d12 = v1[e4 * 4 + 2] - m4.z;
            float d03 = v0[e4 * 4 + 3] - m4.w, d13 = v1[e4 * 4 + 3] - m4.w;
            float t0 = fmaf(r1_0 * d00, d00, r1_1 * d10 * d10);
            float t1 = fmaf(r1_0 * d01, d01, r1_1 * d11 * d11);
            float t2 = fmaf(r1_0 * d02, d02, r1_1 * d12 * d12);
            float t3 = fmaf(r1_0 * d03, d03, r1_1 * d13 * d13);
            t0 += __shfl_xor(t0, 16, 64); t0 += __shfl_xor(t0, 32, 64);
            t1 += __shfl_xor(t1, 16, 64); t1 += __shfl_xor(t1, 32, 64);
            t2 += __shfl_xor(t2, 16, 64); t2 += __shfl_xor(t2, 32, 64);
            t3 += __shfl_xor(t3, 16, 64); t3 += __shfl_xor(t3, 32, 64);
            if (lane < NOUTV)
                *(float4*)&red[wid][lane][e4 * 4] = make_float4(t0, t1, t2, t3);
        }
        __syncthreads();                                  // (4)
        float sg0 = 0.0f, sg1 = 0.0f;
        #pragma unroll
        for (int w2 = 0; w2 < 8; ++w2) {
            sg0 += red[w2][o_f0][e_f];
            sg1 += red[w2][o_f1][e_f];
        }
        const float ss0 = sg0 + EPSF;
        const float ss1 = sg1 + EPSF;
        const float hl0 = 0.5f * logf(ss0);
        const float hl1 = 0.5f * logf(ss1);
        inv2s_sh[o_f0][e_f] = 0.5f / ss0;
        inv2s_sh[o_f1][e_f] = 0.5f / ss1;
        float arsum_f0 = 0.0f, arsum_f1 = 0.0f;
        #pragma unroll
        for (int w2 = 0; w2 < 8; ++w2) {
            arsum_f0 += red_s[w2][o_f0];
            arsum_f1 += red_s[w2][o_f1];
        }
        float sh0 = hl0, sh1 = hl1;
        sh0 += __shfl_xor(sh0, 1, 64);   sh1 += __shfl_xor(sh1, 1, 64);
        sh0 += __shfl_xor(sh0, 2, 64);   sh1 += __shfl_xor(sh1, 2, 64);
        sh0 += __shfl_xor(sh0, 4, 64);   sh1 += __shfl_xor(sh1, 4, 64);
        sh0 += __shfl_xor(sh0, 8, 64);   sh1 += __shfl_xor(sh1, 8, 64);
        sh0 += __shfl_xor(sh0, 16, 64);  sh1 += __shfl_xor(sh1, 16, 64);
        sh0 += __shfl_xor(sh0, 32, 64);  sh1 += __shfl_xor(sh1, 32, 64);
        if (lane == 0) {
            sumhl_sh[o_f0] = sh0;
            sumhl_sh[o_f1] = sh1;
            const float cost0 = 64.0f * beta_u[o_f0] + arsum_f0 * sh0;
            const float cost1 = 64.0f * beta_u[o_f1] + arsum_f1 * sh1;
            logact_sh[o_f0] = logf(1.0f / (1.0f + expf(-(LBDF * (beta_a[o_f0] - cost0)))));
            logact_sh[o_f1] = logf(1.0f / (1.0f + expf(-(LBDF * (beta_a[o_f1] - cost1)))));
        }
        __syncthreads();                                  // (5)

        // ---- e_step (per pair; mu/inv2s rows shared since o is shared) ----
        float acc0 = 0.0f, acc1 = 0.0f;
        #pragma unroll
        for (int e4 = 0; e4 < EE / 4; ++e4) {
            const float4 m4 = *(const float4*)&mu_sh[o][e4 * 4];
            const float4 i4 = *(const float4*)&inv2s_sh[o][e4 * 4];
            float d00 = v0[e4 * 4 + 0] - m4.x, d10 = v1[e4 * 4 + 0] - m4.x;
            float d01 = v0[e4 * 4 + 1] - m4.y, d11 = v1[e4 * 4 + 1] - m4.y;
            float d02 = v0[e4 * 4 + 2] - m4.z, d12 = v1[e4 * 4 + 2] - m4.z;
            float d03 = v0[e4 * 4 + 3] - m4.w, d13 = v1[e4 * 4 + 3] - m4.w;
            acc0 = fmaf(d00 * d00, i4.x, acc0);  acc1 = fmaf(d10 * d10, i4.x, acc1);
            acc0 = fmaf(d01 * d01, i4.y, acc0);  acc1 = fmaf(d11 * d11, i4.y, acc1);
            acc0 = fmaf(d02 * d02, i4.z, acc0);  acc1 = fmaf(d12 * d12, i4.z, acc1);
            acc0 = fmaf(d03 * d03, i4.w, acc0);  acc1 = fmaf(d13 * d13, i4.w, acc1);
        }
        float la0 = -acc0 - sumhl_sh[o] - SUM_LN2PI + logact_sh[o];
        float la1 = -acc1 - sumhl_sh[o] - SUM_LN2PI + logact_sh[o];
        if (msk0) la0 = -10000.0f;
        if (msk1) la1 = -10000.0f;
        float mx0 = la0, mx1 = la1;
        mx0 = fmaxf(mx0, __shfl_xor(mx0, 1, 64));  mx1 = fmaxf(mx1, __shfl_xor(mx1, 1, 64));
        mx0 = fmaxf(mx0, __shfl_xor(mx0, 2, 64));  mx1 = fmaxf(mx1, __shfl_xor(mx1, 2, 64));
        mx0 = fmaxf(mx0, __shfl_xor(mx0, 4, 64));  mx1 = fmaxf(mx1, __shfl_xor(mx1, 4, 64));
        mx0 = fmaxf(mx0, __shfl_xor(mx0, 8, 64));  mx1 = fmaxf(mx1, __shfl_xor(mx1, 8, 64));
        const float ex0 = expf(la0 - mx0);
        const float ex1 = expf(la1 - mx1);
        float se0 = ex0, se1 = ex1;
        se0 += __shfl_xor(se0, 1, 64);  se1 += __shfl_xor(se1, 1, 64);
        se0 += __shfl_xor(se0, 2, 64);  se1 += __shfl_xor(se1, 2, 64);
        se0 += __shfl_xor(se0, 4, 64);  se1 += __shfl_xor(se1, 4, 64);
        se0 += __shfl_xor(se0, 8, 64);  se1 += __shfl_xor(se1, 8, 64);
        r_loc0 = ex0 / se0;
        r_loc1 = ex1 / se1;
    }

    out_r[bl * 1024 + n0 * NOUTV + o] = r_loc0;
    out_r[bl * 1024 + n1 * NOUTV + o] = r_loc1;
}

// ---------------------------------------------------------------------------
extern "C" void kernel_launch(void* const* d_in, const int* in_sizes, int n_in,
                              void* d_out, int out_size, void* d_ws, size_t ws_size,
                              hipStream_t stream) {
    const float* inu            = (const float*)d_in[0];
    const unsigned char* mask   = (const unsigned char*)d_in[1];
    const float* ctx            = (const float*)d_in[2];
    const float* rw             = (const float*)d_in[3];
    const float* Wu             = (const float*)d_in[4];
    const float* bu             = (const float*)d_in[5];
    const float* Wc             = (const float*)d_in[6];
    const float* bc             = (const float*)d_in[7];
    const float* Wv             = (const float*)d_in[8];
    const float* bv             = (const float*)d_in[9];
    const float* Wa             = (const float*)d_in[10];
    const float* ba             = (const float*)d_in[11];
    const float* beta_u         = (const float*)d_in[12];
    const float* beta_a         = (const float*)d_in[13];

    float* u_ws = (float*)d_ws;                       // B*NIN*NOUT*E = 524288 f32
    float* c_ws = u_ws + (size_t)BB * NINV * NOUTV * EE;
    float* a_ws = c_ws + (size_t)BB * LL * EE;        // B*NIN = 512 f32

    float* out_mu = (float*)d_out;
    float* out_r  = out_mu + (size_t)BB * LL * NOUTV * EE;

    prep_kernel<<<BB * LL + BB, 64, 0, stream>>>(ctx, Wc, bc, inu, Wa, ba, c_ws, a_ws);
    priors_u_kernel<<<NINV * NOUTV, 256, 0, stream>>>(inu, rw, Wu, bu, u_ws);
    votes_em_kernel<<<BB * LL, 512, 0, stream>>>(u_ws, c_ws, a_ws, mask, Wv, bv,
                                                 beta_u, beta_a, out_mu, out_r);
}